// Round 11
// baseline (5859.093 us; speedup 1.0000x reference)
//
#include <hip/hip_runtime.h>
#include <math.h>

#define BTOT 1024
#define LEN  2048
#define T    100
#define HID  128

// time-embedding dim constants (f64 argument scaling, f32 sincos)
#define C1 0.025118864315095794
#define C2 6.309573444801933e-04
#define C3 1.5848931924611134e-05
#define C4 3.9810717055349735e-07

#define TEMB(td) \
  float d0 = sinf((float)(td)); \
  float d1 = cosf((float)((td) * C1)); \
  float d2 = sinf((float)((td) * C2)); \
  float d3 = cosf((float)((td) * C3)); \
  float d4 = sinf((float)((td) * C4));

__device__ __forceinline__ float sig(float x) { return 1.0f / (1.0f + expf(-x)); }

// DPP-based add: x + x_from_permuted_lane (VALU pipe, not DS pipe).
template <int CTRL>
__device__ __forceinline__ float dppadd(float x) {
  int r = __builtin_amdgcn_update_dpp(0, __float_as_int(x), CTRL, 0xF, 0xF, false);
  return x + __int_as_float(r);
}
// full 64-lane sum; result valid in lane 0.
__device__ __forceinline__ float wred(float x) {
  x = dppadd<0xB1>(x);    // quad_perm xor1
  x = dppadd<0x4E>(x);    // quad_perm xor2
  x = dppadd<0x124>(x);   // row_ror:4
  x = dppadd<0x128>(x);   // row_ror:8
  x += __shfl_xor(x, 16);
  x += __shfl_xor(x, 32);
  return x;
}
// 8-lane-group sum; xor1 + xor2 + half_mirror(0x141) -- validated round 10.
#define RED8(x) { x = dppadd<0xB1>(x); x = dppadd<0x4E>(x); x = dppadd<0x141>(x); }

// ---------------- Phase A: attention precompute (unchanged from round 10) ----------------
__global__ __attribute__((amdgpu_flat_work_group_size(256, 256), amdgpu_num_vgpr(128)))
void attn_k(const float* __restrict__ ta1,
            const float* __restrict__ ta2,
            float* __restrict__ att) {
  const int b = blockIdx.x, tid = threadIdx.x;
  const int wave = tid >> 6, lane = tid & 63;

  __shared__ float qlds[T][8];
  __shared__ float strip[4][T][8];

  if (tid < T) {
    double ct = (double)(tid + 1) * 0.1;
    TEMB(ct);
    qlds[tid][0] = d0 * 0.35355339059327373f;
    qlds[tid][1] = d1 * 0.35355339059327373f;
    qlds[tid][2] = d2 * 0.35355339059327373f;
    qlds[tid][3] = d3 * 0.35355339059327373f;
    qlds[tid][4] = d4 * 0.35355339059327373f;
  }

#define E5(i) float e##i##_0, e##i##_1, e##i##_2, e##i##_3, e##i##_4;
  E5(0) E5(1) E5(2) E5(3) E5(4) E5(5) E5(6) E5(7)
  E5(8) E5(9) E5(10) E5(11) E5(12) E5(13) E5(14) E5(15)
#undef E5
#define STAGE(i, expr) { double td_ = (double)(expr); \
    e##i##_0 = sinf((float)td_); \
    e##i##_1 = cosf((float)(td_ * C1)); \
    e##i##_2 = sinf((float)(td_ * C2)); \
    e##i##_3 = cosf((float)(td_ * C3)); \
    e##i##_4 = sinf((float)(td_ * C4)); }
  STAGE(0,  ta1[b * LEN + tid +    0])
  STAGE(1,  ta1[b * LEN + tid +  256])
  STAGE(2,  ta1[b * LEN + tid +  512])
  STAGE(3,  ta1[b * LEN + tid +  768])
  STAGE(4,  ta1[b * LEN + tid + 1024])
  STAGE(5,  ta1[b * LEN + tid + 1280])
  STAGE(6,  ta1[b * LEN + tid + 1536])
  STAGE(7,  ta1[b * LEN + tid + 1792])
  STAGE(8,  ta2[b * LEN + tid +    0])
  STAGE(9,  ta2[b * LEN + tid +  256])
  STAGE(10, ta2[b * LEN + tid +  512])
  STAGE(11, ta2[b * LEN + tid +  768])
  STAGE(12, ta2[b * LEN + tid + 1024])
  STAGE(13, ta2[b * LEN + tid + 1280])
  STAGE(14, ta2[b * LEN + tid + 1536])
  STAGE(15, ta2[b * LEN + tid + 1792])
#undef STAGE
#define PIN5(i) asm volatile("" : "+v"(e##i##_0), "+v"(e##i##_1), \
    "+v"(e##i##_2), "+v"(e##i##_3), "+v"(e##i##_4));
  PIN5(0) PIN5(1) PIN5(2) PIN5(3) PIN5(4) PIN5(5) PIN5(6) PIN5(7)
  PIN5(8) PIN5(9) PIN5(10) PIN5(11) PIN5(12) PIN5(13) PIN5(14) PIN5(15)
#undef PIN5

  __syncthreads();

  for (int t = 0; t < T; t++) {
    const float4 qv = *(const float4*)&qlds[t][0];
    const float q4 = qlds[t][4];
    float Wx = 0.f, Wy = 0.f, Wz = 0.f, Ww = 0.f, W4 = 0.f, sA = 0.f, sB = 0.f;
#define EV(i, S) { \
    float s = fmaf(qv.x, e##i##_0, fmaf(qv.y, e##i##_1, \
              fmaf(qv.z, e##i##_2, fmaf(qv.w, e##i##_3, q4 * e##i##_4)))); \
    float e = __expf(s); S += e; \
    Wx = fmaf(e, e##i##_0, Wx); Wy = fmaf(e, e##i##_1, Wy); \
    Wz = fmaf(e, e##i##_2, Wz); Ww = fmaf(e, e##i##_3, Ww); \
    W4 = fmaf(e, e##i##_4, W4); }
    EV(0, sA) EV(1, sA) EV(2, sA) EV(3, sA)
    EV(4, sA) EV(5, sA) EV(6, sA) EV(7, sA)
    EV(8, sB) EV(9, sB) EV(10, sB) EV(11, sB)
    EV(12, sB) EV(13, sB) EV(14, sB) EV(15, sB)
#undef EV

    float r0 = wred(Wx), r1 = wred(Wy), r2 = wred(Wz), r3 = wred(Ww);
    float r4 = wred(W4), r5 = wred(sA), r6 = wred(sB);
    if (lane == 0) {
      *(float4*)&strip[wave][t][0] = make_float4(r0, r1, r2, r3);
      strip[wave][t][4] = r4; strip[wave][t][5] = r5; strip[wave][t][6] = r6;
    }
  }
  __syncthreads();

  if (tid < T) {
    float4 a0 = *(float4*)&strip[0][tid][0], b0 = *(float4*)&strip[0][tid][4];
    float4 a1 = *(float4*)&strip[1][tid][0], b1 = *(float4*)&strip[1][tid][4];
    float4 a2 = *(float4*)&strip[2][tid][0], b2 = *(float4*)&strip[2][tid][4];
    float4 a3 = *(float4*)&strip[3][tid][0], b3 = *(float4*)&strip[3][tid][4];
    float f0 = a0.x + a1.x + a2.x + a3.x;
    float f1 = a0.y + a1.y + a2.y + a3.y;
    float f2 = a0.z + a1.z + a2.z + a3.z;
    float f3 = a0.w + a1.w + a2.w + a3.w;
    float f4 = b0.x + b1.x + b2.x + b3.x;
    float f5 = b0.y + b1.y + b2.y + b3.y;
    float f6 = b0.z + b1.z + b2.z + b3.z;
    float inv = 1.0f / (f5 + f6);
    float* o8 = &att[(size_t)b * (T * 8) + (size_t)tid * 8];
    o8[0] = f0 * inv; o8[1] = f1 * inv; o8[2] = f2 * inv;
    o8[3] = f3 * inv; o8[4] = f4 * inv;
    o8[5] = 0.f; o8[6] = f5 * inv; o8[7] = f6 * inv;
  }
}

// ---------------- Phase B: LSTM, R=4 tiling + STREAMED weights ----------------
// ROUND-11: round-10 spilled 178 MB/dispatch: 1024-thread blocks force 80
// weight floats/thread but the allocator is hard-locked at 64 VGPRs (6 rounds
// of launch_bounds/waves_per_eu all ignored). So: DON'T hold weights. Stream
// all 80 per t as 20 dwordx4 from L2 (305 KB set, L2-resident) through
// iteration-opaque base pointers (asm "+v" on the POINTERS inside the loop
// blocks LICM re-hoisting). Live set ~55-60 regs -> fits 64, zero spill.
// DS stays at round-10's 320 insts/CU/t (x reads only). Whh chunks are 16B
// aligned (row*128 + 4k); Wih-region chunks (s<=1) take a scalar path.
#define XE(tb, b, e) (((tb) * 4 + (b)) * 160 + (e))

__global__ __attribute__((amdgpu_flat_work_group_size(1024, 1024), amdgpu_num_vgpr(128)))
void lstm_k(const float* __restrict__ att,
            const float* __restrict__ u,
            const float* __restrict__ Wih,
            const float* __restrict__ Whh,
            const float* __restrict__ bih,
            const float* __restrict__ bhh,
            const float* __restrict__ w1g,
            const float* __restrict__ b1g,
            const float* __restrict__ w2g,
            const float* __restrict__ b2g,
            float* __restrict__ out) {
  const int tid = threadIdx.x;
  const int bg = blockIdx.x * 4;
  const int q = tid >> 3, s = tid & 7;       // channel, 20-col segment
  const int wave = tid >> 6, lane = tid & 63;
  const int s5 = s * 5;

  __shared__ float4 xls4[2][4][40];          // dbuf [x(21)|pad|hx(128)|pad] per batch
  __shared__ float4 red4[2][4][4];           // per-wave head partials
  __shared__ int stL[2][4], stD[2][4], stH[2][4];
  float* xf = (float*)xls4;
  float* rf = (float*)red4;

  float bb0 = bih[q] + bhh[q];
  float bb1 = bih[q + 128] + bhh[q + 128];
  float bb2 = bih[q + 256] + bhh[q + 256];
  float bb3 = bih[q + 384] + bhh[q + 384];
  float wv = 0.f;
#pragma unroll
  for (int j = 0; j < 5; j++) wv = fmaf(w2g[j], w1g[j * HID + q], wv);
  float hconst = b2g[0];
#pragma unroll
  for (int j = 0; j < 5; j++) hconst = fmaf(w2g[j], b1g[j], hconst);
  asm volatile("" : "+v"(bb0), "+v"(bb1), "+v"(bb2), "+v"(bb3), "+v"(wv), "+v"(hconst));
  float cx0 = 0.f, cx1 = 0.f, cx2 = 0.f, cx3 = 0.f;

  for (int i = tid; i < 2 * 4 * 160; i += 1024) xf[i] = 0.f;
  if (tid < 4) { stL[0][tid] = 0; stD[0][tid] = 0; stH[0][tid] = 0; }
  __syncthreads();

  // x(t=0) into buffer 0: att + ct_emb(0.1); m_emb stays 0 (no event yet)
  if (tid < 32) {
    int b = tid >> 3, j = tid & 7;
    xf[XE(0, b, j)] = att[(size_t)(bg + b) * (T * 8) + j];
  } else if (tid >= 64 && tid < 84) {
    int s2 = tid - 64, b = s2 / 5, j = s2 % 5;
    TEMB(0.1);
    xf[XE(0, b, 16 + j)] = (j == 0) ? d0 : (j == 1) ? d1 : (j == 2) ? d2 : (j == 3) ? d3 : d4;
  }
  __syncthreads();

  // opaque weight base pointers (re-blurred每 iteration to kill LICM)
  const float* wi_p = Wih;
  const float* wh_p = Whh;

  // scalar Wih-region element (e in padded [0,24) coords)
#define WSC(g, e) (((e) < 21) ? wi_p[(size_t)(q + 128 * (g)) * 21 + (e)] : 0.f)

  // load chunk (gate g, chunk c): padded cols E..E+3, E = 20s+4c
#define LDW(g, c, dst) { \
    int E_ = 20 * s + 4 * (c); \
    if (E_ >= 24) { \
      dst = *(const float4*)(wh_p + (size_t)(q + 128 * (g)) * HID + (E_ - 24)); \
    } else { \
      dst.x = WSC(g, E_ + 0); dst.y = WSC(g, E_ + 1); \
      dst.z = WSC(g, E_ + 2); dst.w = WSC(g, E_ + 3); \
    } }

#define FM(g, b) a##g##b = fmaf(w##g.x, x##b.x, fmaf(w##g.y, x##b.y, \
    fmaf(w##g.z, x##b.z, fmaf(w##g.w, x##b.w, a##g##b))));

#define CH(c) { \
    float4 w0, w1, w2, w3; \
    LDW(0, c, w0) LDW(1, c, w1) LDW(2, c, w2) LDW(3, c, w3) \
    float4 x0 = xls4[tb][0][s5 + (c)], x1 = xls4[tb][1][s5 + (c)], \
           x2 = xls4[tb][2][s5 + (c)], x3 = xls4[tb][3][s5 + (c)]; \
    FM(0, 0) FM(0, 1) FM(0, 2) FM(0, 3) \
    FM(1, 0) FM(1, 1) FM(1, 2) FM(1, 3) \
    FM(2, 0) FM(2, 1) FM(2, 2) FM(2, 3) \
    FM(3, 0) FM(3, 1) FM(3, 2) FM(3, 3) }

#define CELL(b, cxv) { \
  float gi = a0##b + bb0, gf = a1##b + bb1, gG = a2##b + bb2, go = a3##b + bb3; \
  cxv = sig(gf) * cxv + sig(gi) * tanhf(gG); \
  float hn = sig(go) * tanhf(cxv); \
  xf[XE(tb1, b, 24 + q)] = hn; \
  pb##b = wv * hn; }

#define CALCEV(bb) \
    float4 r0 = red4[tb][bb][0], r1 = red4[tb][bb][1], \
           r2 = red4[tb][bb][2], r3 = red4[tb][bb][3]; \
    float z_ = hconst + (((r0.x + r0.y) + (r0.z + r0.w)) + ((r1.x + r1.y) + (r1.z + r1.w))) \
                      + (((r2.x + r2.y) + (r2.z + r2.w)) + ((r3.x + r3.y) + (r3.z + r3.w))); \
    float hz_ = 1.f / (1.f + expf(-z_)); \
    int ev_ = (u[(size_t)(bg + (bb)) * T + t] < hz_) ? 1 : 0; \
    int lastp_ = ev_ ? (t + 1) : stL[tb][bb]; \
    int hasp_ = stH[tb][bb] | ev_; \
    int dynp_ = ev_ ? 0 : (stD[tb][bb] + 1);

  for (int t = 0; t < T; t++) {
    const int tb = t & 1, tb1 = tb ^ 1;
    // blur the weight pointers: loads below cannot be hoisted/CSE'd across t
    asm volatile("" : "+v"(wi_p), "+v"(wh_p));

    // ---- P1: acc[g][b] over this thread's 20-col segment ----
    float a00 = 0.f, a01 = 0.f, a02 = 0.f, a03 = 0.f,
          a10 = 0.f, a11 = 0.f, a12 = 0.f, a13 = 0.f,
          a20 = 0.f, a21 = 0.f, a22 = 0.f, a23 = 0.f,
          a30 = 0.f, a31 = 0.f, a32 = 0.f, a33 = 0.f;
    CH(0) CH(1) CH(2) CH(3) CH(4)

    RED8(a00) RED8(a01) RED8(a02) RED8(a03)
    RED8(a10) RED8(a11) RED8(a12) RED8(a13)
    RED8(a20) RED8(a21) RED8(a22) RED8(a23)
    RED8(a30) RED8(a31) RED8(a32) RED8(a33)

    float pb0 = 0.f, pb1 = 0.f, pb2 = 0.f, pb3 = 0.f;
    if (s == 0) {            // lane holds complete i,f,g,o for channel q
      CELL(0, cx0) CELL(1, cx1) CELL(2, cx2) CELL(3, cx3)
    }
    pb0 = wred(pb0); pb1 = wred(pb1); pb2 = wred(pb2); pb3 = wred(pb3);
    if (lane == 0) {
      rf[(tb * 4 + 0) * 16 + wave] = pb0;
      rf[(tb * 4 + 1) * 16 + wave] = pb1;
      rf[(tb * 4 + 2) * 16 + wave] = pb2;
      rf[(tb * 4 + 3) * 16 + wave] = pb3;
    }
    __syncthreads();

    // ---- P3: hazard/event finalize + build x(t+1) (redundant CALCEV) ----
    if (tid < 4) {
      int b = tid;
      CALCEV(b);
      out[(size_t)t * BTOT + bg + b] = hz_;
      out[(size_t)T * BTOT + (size_t)t * BTOT + bg + b] = ev_ ? 1.f : 0.f;
      stL[tb1][b] = lastp_; stH[tb1][b] = hasp_; stD[tb1][b] = dynp_;
    }
    if (t < T - 1) {
      if (tid < 32) {
        int b = tid >> 3, j = tid & 7;
        xf[XE(tb1, b, j)] = att[(size_t)(bg + b) * (T * 8) + (size_t)(t + 1) * 8 + j];
      } else if (tid < 52) {
        int s2 = tid - 32, b = s2 / 5, j = s2 % 5;
        CALCEV(b);
        float v = 0.f;
        if (hasp_) {
          double td = (double)lastp_ * 0.1;
          TEMB(td);
          v = (j == 0) ? d0 : (j == 1) ? d1 : (j == 2) ? d2 : (j == 3) ? d3 : d4;
        }
        xf[XE(tb1, b, 8 + j)] = v;
      } else if (tid < 64) {
        int s2 = tid - 52, b = s2 / 3, j = s2 % 3;
        CALCEV(b);
        xf[XE(tb1, b, 13 + j)] = (j == 0 && hasp_) ? 1.f : 0.f;
      } else if (tid < 84) {
        int s2 = tid - 64, b = s2 / 5, j = s2 % 5;
        CALCEV(b);
        double td = (double)(dynp_ + 1) * 0.1;
        TEMB(td);
        xf[XE(tb1, b, 16 + j)] =
            (j == 0) ? d0 : (j == 1) ? d1 : (j == 2) ? d2 : (j == 3) ? d3 : d4;
      }
    }
    __syncthreads();
  }
#undef CALCEV
#undef CELL
#undef CH
#undef FM
#undef LDW
#undef WSC
}

extern "C" void kernel_launch(void* const* d_in, const int* in_sizes, int n_in,
                              void* d_out, int out_size, void* d_ws, size_t ws_size,
                              hipStream_t stream) {
  const float* ta1 = (const float*)d_in[0];
  const float* ta2 = (const float*)d_in[1];
  const float* u   = (const float*)d_in[2];
  const float* Wih = (const float*)d_in[3];
  const float* Whh = (const float*)d_in[4];
  const float* bih = (const float*)d_in[5];
  const float* bhh = (const float*)d_in[6];
  const float* w1  = (const float*)d_in[7];
  const float* b1  = (const float*)d_in[8];
  const float* w2  = (const float*)d_in[9];
  const float* b2  = (const float*)d_in[10];
  float* out = (float*)d_out;
  float* att = (float*)d_ws;   // 1024*100*8 floats = 3.28 MB scratch

  attn_k<<<dim3(BTOT), dim3(256), 0, stream>>>(ta1, ta2, att);
  lstm_k<<<dim3(BTOT / 4), dim3(1024), 0, stream>>>(att, u, Wih, Whh, bih, bhh,
                                                    w1, b1, w2, b2, out);
}

// Round 12
// 1050.781 us; speedup vs baseline: 5.5759x; 5.5759x over previous
//
#include <hip/hip_runtime.h>
#include <math.h>

#define BTOT 1024
#define LEN  2048
#define T    100
#define HID  128

// ws layout: [0, 320KB) = transposed weights wsT; att at +327680 bytes.
#define ATT_OFF_FLOATS 81920

// time-embedding dim constants (f64 argument scaling, f32 sincos)
#define C1 0.025118864315095794
#define C2 6.309573444801933e-04
#define C3 1.5848931924611134e-05
#define C4 3.9810717055349735e-07

#define TEMB(td) \
  float d0 = sinf((float)(td)); \
  float d1 = cosf((float)((td) * C1)); \
  float d2 = sinf((float)((td) * C2)); \
  float d3 = cosf((float)((td) * C3)); \
  float d4 = sinf((float)((td) * C4));

__device__ __forceinline__ float sig(float x) { return 1.0f / (1.0f + expf(-x)); }

// DPP-based add: x + x_from_permuted_lane (VALU pipe, not DS pipe).
template <int CTRL>
__device__ __forceinline__ float dppadd(float x) {
  int r = __builtin_amdgcn_update_dpp(0, __float_as_int(x), CTRL, 0xF, 0xF, false);
  return x + __int_as_float(r);
}
// full 64-lane sum; result valid in lane 0.
__device__ __forceinline__ float wred(float x) {
  x = dppadd<0xB1>(x);    // quad_perm xor1
  x = dppadd<0x4E>(x);    // quad_perm xor2
  x = dppadd<0x124>(x);   // row_ror:4
  x = dppadd<0x128>(x);   // row_ror:8
  x += __shfl_xor(x, 16);
  x += __shfl_xor(x, 32);
  return x;
}
// 8-lane-group sum; xor1 + xor2 + half_mirror(0x141) -- validated round 10.
#define RED8(x) { x = dppadd<0xB1>(x); x = dppadd<0x4E>(x); x = dppadd<0x141>(x); }

// ---------------- Weight pre-transpose (one-time, 327 KB) ----------------
// wsT[(g*5+c)*1024 + tid] = rows q+128g (q=tid>>3), padded cols 20(tid&7)+4c..+3
// so lstm_k's per-t loads are PERFECTLY COALESCED across the wave (round-11
// lesson: same stream GATHERED by row = 3.8 GB HBM traffic, 5.7 ms).
__global__ void wprep_k(const float* __restrict__ Wih,
                        const float* __restrict__ Whh,
                        float4* __restrict__ wsT) {
  int i = blockIdx.x * 1024 + threadIdx.x;          // 20 blocks x 1024 = 20480
  int g = i / 5120;
  int rem = i - g * 5120;
  int c = rem >> 10;
  int t2 = rem & 1023;
  int q = t2 >> 3, s = t2 & 7;
  int row = q + 128 * g;
  int E = 20 * s + 4 * c;
  float v[4];
#pragma unroll
  for (int k = 0; k < 4; k++) {
    int e = E + k;
    v[k] = (e < 21) ? Wih[row * 21 + e]
         : (e < 24) ? 0.f
         : (e < 152) ? Whh[row * HID + (e - 24)]
         : 0.f;
  }
  wsT[i] = make_float4(v[0], v[1], v[2], v[3]);
}

// ---------------- Phase A: attention, 8 events/thread (fits 64 VGPR) ----------------
// 1024 blocks x 512 threads (2 blocks/CU, 4 waves/SIMD). 40 emb floats +
// ~20 misc ~= 60 live regs -> no spill at the hard 64-VGPR cap (rounds 2-8:
// 80-float version force-spilled ~30 floats/t through scratch).
__global__ __attribute__((amdgpu_flat_work_group_size(512, 512)))
void attn_k(const float* __restrict__ ta1,
            const float* __restrict__ ta2,
            float* __restrict__ att) {
  const int b = blockIdx.x, tid = threadIdx.x;
  const int wave = tid >> 6, lane = tid & 63;

  __shared__ float qlds[T][8];
  __shared__ float strip[8][T][8];

  if (tid < T) {
    double ct = (double)(tid + 1) * 0.1;
    TEMB(ct);
    qlds[tid][0] = d0 * 0.35355339059327373f;  // fold 1/sqrt(8)
    qlds[tid][1] = d1 * 0.35355339059327373f;
    qlds[tid][2] = d2 * 0.35355339059327373f;
    qlds[tid][3] = d3 * 0.35355339059327373f;
    qlds[tid][4] = d4 * 0.35355339059327373f;
  }

#define E5(i) float e##i##_0, e##i##_1, e##i##_2, e##i##_3, e##i##_4;
  E5(0) E5(1) E5(2) E5(3) E5(4) E5(5) E5(6) E5(7)
#undef E5
#define STAGE(i, expr) { double td_ = (double)(expr); \
    e##i##_0 = sinf((float)td_); \
    e##i##_1 = cosf((float)(td_ * C1)); \
    e##i##_2 = sinf((float)(td_ * C2)); \
    e##i##_3 = cosf((float)(td_ * C3)); \
    e##i##_4 = sinf((float)(td_ * C4)); }
  STAGE(0, ta1[b * LEN + tid +    0])
  STAGE(1, ta1[b * LEN + tid +  512])
  STAGE(2, ta1[b * LEN + tid + 1024])
  STAGE(3, ta1[b * LEN + tid + 1536])
  STAGE(4, ta2[b * LEN + tid +    0])
  STAGE(5, ta2[b * LEN + tid +  512])
  STAGE(6, ta2[b * LEN + tid + 1024])
  STAGE(7, ta2[b * LEN + tid + 1536])
#undef STAGE
#define PIN5(i) asm volatile("" : "+v"(e##i##_0), "+v"(e##i##_1), \
    "+v"(e##i##_2), "+v"(e##i##_3), "+v"(e##i##_4));
  PIN5(0) PIN5(1) PIN5(2) PIN5(3) PIN5(4) PIN5(5) PIN5(6) PIN5(7)
#undef PIN5

  __syncthreads();

  for (int t = 0; t < T; t++) {
    const float4 qv = *(const float4*)&qlds[t][0];
    const float q4 = qlds[t][4];
    float Wx = 0.f, Wy = 0.f, Wz = 0.f, Ww = 0.f, W4 = 0.f, sA = 0.f, sB = 0.f;
    // scores bounded (|q.k|/sqrt8 <= 1.77): exp without max-sub, f32-safe
    // (validated absmax 0.0 rounds 1-3, 6-8, 10, 11)
#define EV(i, S) { \
    float s = fmaf(qv.x, e##i##_0, fmaf(qv.y, e##i##_1, \
              fmaf(qv.z, e##i##_2, fmaf(qv.w, e##i##_3, q4 * e##i##_4)))); \
    float e = __expf(s); S += e; \
    Wx = fmaf(e, e##i##_0, Wx); Wy = fmaf(e, e##i##_1, Wy); \
    Wz = fmaf(e, e##i##_2, Wz); Ww = fmaf(e, e##i##_3, Ww); \
    W4 = fmaf(e, e##i##_4, W4); }
    EV(0, sA) EV(1, sA) EV(2, sA) EV(3, sA)
    EV(4, sB) EV(5, sB) EV(6, sB) EV(7, sB)
#undef EV

    float r0 = wred(Wx), r1 = wred(Wy), r2 = wred(Wz), r3 = wred(Ww);
    float r4 = wred(W4), r5 = wred(sA), r6 = wred(sB);
    if (lane == 0) {
      *(float4*)&strip[wave][t][0] = make_float4(r0, r1, r2, r3);
      strip[wave][t][4] = r4; strip[wave][t][5] = r5; strip[wave][t][6] = r6;
    }
  }
  __syncthreads();

  if (tid < T) {
    float f0 = 0.f, f1 = 0.f, f2 = 0.f, f3 = 0.f, f4 = 0.f, f5 = 0.f, f6 = 0.f;
#pragma unroll
    for (int w = 0; w < 8; w++) {
      float4 a = *(float4*)&strip[w][tid][0];
      float4 bq = *(float4*)&strip[w][tid][4];
      f0 += a.x; f1 += a.y; f2 += a.z; f3 += a.w;
      f4 += bq.x; f5 += bq.y; f6 += bq.z;
    }
    float inv = 1.0f / (f5 + f6);
    float* o8 = &att[(size_t)b * (T * 8) + (size_t)tid * 8];
    o8[0] = f0 * inv; o8[1] = f1 * inv; o8[2] = f2 * inv;
    o8[3] = f3 * inv; o8[4] = f4 * inv;
    o8[5] = 0.f; o8[6] = f5 * inv; o8[7] = f6 * inv;
  }
}

// ---------------- Phase B: LSTM, R=4 tiling + COALESCED streamed weights ----------------
// Thread (q,s): channel q's 4 gate rows x 20-col segment s. Per t: 20
// coalesced dwordx4 weight loads from L2-resident wsT (1 KB/wave-inst) +
// 20 b128 LDS x-broadcasts (320 DS insts/CU/t, conflict-free bank map).
// Live set ~58 regs -> fits the hard 64-VGPR cap, zero per-iteration spill.
// Ceiling: L1 delivery 327 KB/t/CU @ 64 B/cyc = 5.1K cyc = 2.1 us/t.
#define XE(tb, b, e) (((tb) * 4 + (b)) * 160 + (e))

__global__ __attribute__((amdgpu_flat_work_group_size(1024, 1024)))
void lstm_k(const float* __restrict__ att,
            const float* __restrict__ u,
            const float4* __restrict__ wT,
            const float* __restrict__ bih,
            const float* __restrict__ bhh,
            const float* __restrict__ w1g,
            const float* __restrict__ b1g,
            const float* __restrict__ w2g,
            const float* __restrict__ b2g,
            float* __restrict__ out) {
  const int tid = threadIdx.x;
  const int bg = blockIdx.x * 4;
  const int q = tid >> 3, s = tid & 7;       // channel, 20-col segment
  const int wave = tid >> 6, lane = tid & 63;
  const int s5 = s * 5;

  __shared__ float4 xls4[2][4][40];          // dbuf [x(21)|pad|hx(128)|pad] per batch
  __shared__ float4 red4[2][4][4];           // per-wave head partials
  __shared__ int stL[2][4], stD[2][4], stH[2][4];
  float* xf = (float*)xls4;
  float* rf = (float*)red4;

  float bb0 = bih[q] + bhh[q];
  float bb1 = bih[q + 128] + bhh[q + 128];
  float bb2 = bih[q + 256] + bhh[q + 256];
  float bb3 = bih[q + 384] + bhh[q + 384];
  float wv = 0.f;
#pragma unroll
  for (int j = 0; j < 5; j++) wv = fmaf(w2g[j], w1g[j * HID + q], wv);
  float hconst = b2g[0];
#pragma unroll
  for (int j = 0; j < 5; j++) hconst = fmaf(w2g[j], b1g[j], hconst);
  asm volatile("" : "+v"(bb0), "+v"(bb1), "+v"(bb2), "+v"(bb3), "+v"(wv), "+v"(hconst));
  float cx0 = 0.f, cx1 = 0.f, cx2 = 0.f, cx3 = 0.f;

  for (int i = tid; i < 2 * 4 * 160; i += 1024) xf[i] = 0.f;
  if (tid < 4) { stL[0][tid] = 0; stD[0][tid] = 0; stH[0][tid] = 0; }
  __syncthreads();

  // x(t=0) into buffer 0: att + ct_emb(0.1); m_emb stays 0 (no event yet)
  if (tid < 32) {
    int b = tid >> 3, j = tid & 7;
    xf[XE(0, b, j)] = att[(size_t)(bg + b) * (T * 8) + j];
  } else if (tid >= 64 && tid < 84) {
    int s2 = tid - 64, b = s2 / 5, j = s2 % 5;
    TEMB(0.1);
    xf[XE(0, b, 16 + j)] = (j == 0) ? d0 : (j == 1) ? d1 : (j == 2) ? d2 : (j == 3) ? d3 : d4;
  }
  __syncthreads();

  const float4* wTp = wT;   // blurred per iteration: no LICM re-hoist -> no spill

#define FM(g, b) a##g##b = fmaf(w##g.x, x##b.x, fmaf(w##g.y, x##b.y, \
    fmaf(w##g.z, x##b.z, fmaf(w##g.w, x##b.w, a##g##b))));

#define CH(c) { \
    float4 w0 = wTp[(0 * 5 + (c)) * 1024 + tid]; \
    float4 w1 = wTp[(1 * 5 + (c)) * 1024 + tid]; \
    float4 w2 = wTp[(2 * 5 + (c)) * 1024 + tid]; \
    float4 w3 = wTp[(3 * 5 + (c)) * 1024 + tid]; \
    float4 x0 = xls4[tb][0][s5 + (c)], x1 = xls4[tb][1][s5 + (c)], \
           x2 = xls4[tb][2][s5 + (c)], x3 = xls4[tb][3][s5 + (c)]; \
    FM(0, 0) FM(0, 1) FM(0, 2) FM(0, 3) \
    FM(1, 0) FM(1, 1) FM(1, 2) FM(1, 3) \
    FM(2, 0) FM(2, 1) FM(2, 2) FM(2, 3) \
    FM(3, 0) FM(3, 1) FM(3, 2) FM(3, 3) }

#define CELL(b, cxv) { \
  float gi = a0##b + bb0, gf = a1##b + bb1, gG = a2##b + bb2, go = a3##b + bb3; \
  cxv = sig(gf) * cxv + sig(gi) * tanhf(gG); \
  float hn = sig(go) * tanhf(cxv); \
  xf[XE(tb1, b, 24 + q)] = hn; \
  pb##b = wv * hn; }

#define CALCEV(bb) \
    float4 r0 = red4[tb][bb][0], r1 = red4[tb][bb][1], \
           r2 = red4[tb][bb][2], r3 = red4[tb][bb][3]; \
    float z_ = hconst + (((r0.x + r0.y) + (r0.z + r0.w)) + ((r1.x + r1.y) + (r1.z + r1.w))) \
                      + (((r2.x + r2.y) + (r2.z + r2.w)) + ((r3.x + r3.y) + (r3.z + r3.w))); \
    float hz_ = 1.f / (1.f + expf(-z_)); \
    int ev_ = (u[(size_t)(bg + (bb)) * T + t] < hz_) ? 1 : 0; \
    int lastp_ = ev_ ? (t + 1) : stL[tb][bb]; \
    int hasp_ = stH[tb][bb] | ev_; \
    int dynp_ = ev_ ? 0 : (stD[tb][bb] + 1);

  for (int t = 0; t < T; t++) {
    const int tb = t & 1, tb1 = tb ^ 1;
    asm volatile("" : "+v"(wTp));

    // ---- P1: acc[g][b] over this thread's 20-col segment ----
    float a00 = 0.f, a01 = 0.f, a02 = 0.f, a03 = 0.f,
          a10 = 0.f, a11 = 0.f, a12 = 0.f, a13 = 0.f,
          a20 = 0.f, a21 = 0.f, a22 = 0.f, a23 = 0.f,
          a30 = 0.f, a31 = 0.f, a32 = 0.f, a33 = 0.f;
    CH(0) CH(1) CH(2) CH(3) CH(4)

    RED8(a00) RED8(a01) RED8(a02) RED8(a03)
    RED8(a10) RED8(a11) RED8(a12) RED8(a13)
    RED8(a20) RED8(a21) RED8(a22) RED8(a23)
    RED8(a30) RED8(a31) RED8(a32) RED8(a33)

    float pb0 = 0.f, pb1 = 0.f, pb2 = 0.f, pb3 = 0.f;
    if (s == 0) {            // lane holds complete i,f,g,o for channel q
      CELL(0, cx0) CELL(1, cx1) CELL(2, cx2) CELL(3, cx3)
    }
    pb0 = wred(pb0); pb1 = wred(pb1); pb2 = wred(pb2); pb3 = wred(pb3);
    if (lane == 0) {
      rf[(tb * 4 + 0) * 16 + wave] = pb0;
      rf[(tb * 4 + 1) * 16 + wave] = pb1;
      rf[(tb * 4 + 2) * 16 + wave] = pb2;
      rf[(tb * 4 + 3) * 16 + wave] = pb3;
    }
    __syncthreads();

    // ---- P3: hazard/event finalize + build x(t+1) (redundant CALCEV) ----
    if (tid < 4) {
      int b = tid;
      CALCEV(b);
      out[(size_t)t * BTOT + bg + b] = hz_;
      out[(size_t)T * BTOT + (size_t)t * BTOT + bg + b] = ev_ ? 1.f : 0.f;
      stL[tb1][b] = lastp_; stH[tb1][b] = hasp_; stD[tb1][b] = dynp_;
    }
    if (t < T - 1) {
      if (tid < 32) {
        int b = tid >> 3, j = tid & 7;
        xf[XE(tb1, b, j)] = att[(size_t)(bg + b) * (T * 8) + (size_t)(t + 1) * 8 + j];
      } else if (tid < 52) {
        int s2 = tid - 32, b = s2 / 5, j = s2 % 5;
        CALCEV(b);
        float v = 0.f;
        if (hasp_) {
          double td = (double)lastp_ * 0.1;
          TEMB(td);
          v = (j == 0) ? d0 : (j == 1) ? d1 : (j == 2) ? d2 : (j == 3) ? d3 : d4;
        }
        xf[XE(tb1, b, 8 + j)] = v;
      } else if (tid < 64) {
        int s2 = tid - 52, b = s2 / 3, j = s2 % 3;
        CALCEV(b);
        xf[XE(tb1, b, 13 + j)] = (j == 0 && hasp_) ? 1.f : 0.f;
      } else if (tid < 84) {
        int s2 = tid - 64, b = s2 / 5, j = s2 % 5;
        CALCEV(b);
        double td = (double)(dynp_ + 1) * 0.1;
        TEMB(td);
        xf[XE(tb1, b, 16 + j)] =
            (j == 0) ? d0 : (j == 1) ? d1 : (j == 2) ? d2 : (j == 3) ? d3 : d4;
      }
    }
    __syncthreads();
  }
#undef CALCEV
#undef CELL
#undef CH
#undef FM
}

extern "C" void kernel_launch(void* const* d_in, const int* in_sizes, int n_in,
                              void* d_out, int out_size, void* d_ws, size_t ws_size,
                              hipStream_t stream) {
  const float* ta1 = (const float*)d_in[0];
  const float* ta2 = (const float*)d_in[1];
  const float* u   = (const float*)d_in[2];
  const float* Wih = (const float*)d_in[3];
  const float* Whh = (const float*)d_in[4];
  const float* bih = (const float*)d_in[5];
  const float* bhh = (const float*)d_in[6];
  const float* w1  = (const float*)d_in[7];
  const float* b1  = (const float*)d_in[8];
  const float* w2  = (const float*)d_in[9];
  const float* b2  = (const float*)d_in[10];
  float* out = (float*)d_out;
  float4* wsT = (float4*)d_ws;                           // 327,680 B
  float* att = (float*)d_ws + ATT_OFF_FLOATS;            // 3.28 MB

  wprep_k<<<dim3(20), dim3(1024), 0, stream>>>(Wih, Whh, wsT);
  attn_k<<<dim3(BTOT), dim3(512), 0, stream>>>(ta1, ta2, att);
  lstm_k<<<dim3(BTOT / 4), dim3(1024), 0, stream>>>(att, u, wsT, bih, bhh,
                                                    w1, b1, w2, b2, out);
}

// Round 13
// 835.152 us; speedup vs baseline: 7.0156x; 1.2582x over previous
//
#include <hip/hip_runtime.h>
#include <math.h>

#define BTOT 1024
#define LEN  2048
#define T    100
#define HID  128

// ws layout: [0, 320KB) = transposed weights wsT; att at +327680 bytes.
#define ATT_OFF_FLOATS 81920

// time-embedding dim constants (f64 argument scaling, f32 sincos)
#define C1 0.025118864315095794
#define C2 6.309573444801933e-04
#define C3 1.5848931924611134e-05
#define C4 3.9810717055349735e-07

#define TEMB(td) \
  float d0 = sinf((float)(td)); \
  float d1 = cosf((float)((td) * C1)); \
  float d2 = sinf((float)((td) * C2)); \
  float d3 = cosf((float)((td) * C3)); \
  float d4 = sinf((float)((td) * C4));

__device__ __forceinline__ float sig(float x) { return 1.0f / (1.0f + expf(-x)); }

using v2f = __attribute__((ext_vector_type(2))) float;
__device__ __forceinline__ v2f mkv2(float a, float b) { v2f r; r.x = a; r.y = b; return r; }

// DPP-based add: x + x_from_permuted_lane (VALU pipe, not DS pipe).
template <int CTRL>
__device__ __forceinline__ float dppadd(float x) {
  int r = __builtin_amdgcn_update_dpp(0, __float_as_int(x), CTRL, 0xF, 0xF, false);
  return x + __int_as_float(r);
}
// full 64-lane sum; result valid in lane 0.
__device__ __forceinline__ float wred(float x) {
  x = dppadd<0xB1>(x);    // quad_perm xor1
  x = dppadd<0x4E>(x);    // quad_perm xor2
  x = dppadd<0x124>(x);   // row_ror:4
  x = dppadd<0x128>(x);   // row_ror:8
  x += __shfl_xor(x, 16);
  x += __shfl_xor(x, 32);
  return x;
}
// 8-lane-group sum; xor1 + xor2 + half_mirror(0x141) -- validated round 10+.
#define RED8(x) { x = dppadd<0xB1>(x); x = dppadd<0x4E>(x); x = dppadd<0x141>(x); }

// ---------------- Weight pre-transpose (one-time, 327 KB) ----------------
__global__ void wprep_k(const float* __restrict__ Wih,
                        const float* __restrict__ Whh,
                        float4* __restrict__ wsT) {
  int i = blockIdx.x * 1024 + threadIdx.x;          // 20 blocks x 1024 = 20480
  int g = i / 5120;
  int rem = i - g * 5120;
  int c = rem >> 10;
  int t2 = rem & 1023;
  int q = t2 >> 3, s = t2 & 7;
  int row = q + 128 * g;
  int E = 20 * s + 4 * c;
  float v[4];
#pragma unroll
  for (int k = 0; k < 4; k++) {
    int e = E + k;
    v[k] = (e < 21) ? Wih[row * 21 + e]
         : (e < 24) ? 0.f
         : (e < 152) ? Whh[row * HID + (e - 24)]
         : 0.f;
  }
  wsT[i] = make_float4(v[0], v[1], v[2], v[3]);
}

// ---------------- Phase A: attention (unchanged from round 12, passed) ----------------
__global__ __attribute__((amdgpu_flat_work_group_size(512, 512)))
void attn_k(const float* __restrict__ ta1,
            const float* __restrict__ ta2,
            float* __restrict__ att) {
  const int b = blockIdx.x, tid = threadIdx.x;
  const int wave = tid >> 6, lane = tid & 63;

  __shared__ float qlds[T][8];
  __shared__ float strip[8][T][8];

  if (tid < T) {
    double ct = (double)(tid + 1) * 0.1;
    TEMB(ct);
    qlds[tid][0] = d0 * 0.35355339059327373f;  // fold 1/sqrt(8)
    qlds[tid][1] = d1 * 0.35355339059327373f;
    qlds[tid][2] = d2 * 0.35355339059327373f;
    qlds[tid][3] = d3 * 0.35355339059327373f;
    qlds[tid][4] = d4 * 0.35355339059327373f;
  }

#define E5(i) float e##i##_0, e##i##_1, e##i##_2, e##i##_3, e##i##_4;
  E5(0) E5(1) E5(2) E5(3) E5(4) E5(5) E5(6) E5(7)
#undef E5
#define STAGE(i, expr) { double td_ = (double)(expr); \
    e##i##_0 = sinf((float)td_); \
    e##i##_1 = cosf((float)(td_ * C1)); \
    e##i##_2 = sinf((float)(td_ * C2)); \
    e##i##_3 = cosf((float)(td_ * C3)); \
    e##i##_4 = sinf((float)(td_ * C4)); }
  STAGE(0, ta1[b * LEN + tid +    0])
  STAGE(1, ta1[b * LEN + tid +  512])
  STAGE(2, ta1[b * LEN + tid + 1024])
  STAGE(3, ta1[b * LEN + tid + 1536])
  STAGE(4, ta2[b * LEN + tid +    0])
  STAGE(5, ta2[b * LEN + tid +  512])
  STAGE(6, ta2[b * LEN + tid + 1024])
  STAGE(7, ta2[b * LEN + tid + 1536])
#undef STAGE
#define PIN5(i) asm volatile("" : "+v"(e##i##_0), "+v"(e##i##_1), \
    "+v"(e##i##_2), "+v"(e##i##_3), "+v"(e##i##_4));
  PIN5(0) PIN5(1) PIN5(2) PIN5(3) PIN5(4) PIN5(5) PIN5(6) PIN5(7)
#undef PIN5

  __syncthreads();

  for (int t = 0; t < T; t++) {
    const float4 qv = *(const float4*)&qlds[t][0];
    const float q4 = qlds[t][4];
    float Wx = 0.f, Wy = 0.f, Wz = 0.f, Ww = 0.f, W4 = 0.f, sA = 0.f, sB = 0.f;
#define EV(i, S) { \
    float s = fmaf(qv.x, e##i##_0, fmaf(qv.y, e##i##_1, \
              fmaf(qv.z, e##i##_2, fmaf(qv.w, e##i##_3, q4 * e##i##_4)))); \
    float e = __expf(s); S += e; \
    Wx = fmaf(e, e##i##_0, Wx); Wy = fmaf(e, e##i##_1, Wy); \
    Wz = fmaf(e, e##i##_2, Wz); Ww = fmaf(e, e##i##_3, Ww); \
    W4 = fmaf(e, e##i##_4, W4); }
    EV(0, sA) EV(1, sA) EV(2, sA) EV(3, sA)
    EV(4, sB) EV(5, sB) EV(6, sB) EV(7, sB)
#undef EV

    float r0 = wred(Wx), r1 = wred(Wy), r2 = wred(Wz), r3 = wred(Ww);
    float r4 = wred(W4), r5 = wred(sA), r6 = wred(sB);
    if (lane == 0) {
      *(float4*)&strip[wave][t][0] = make_float4(r0, r1, r2, r3);
      strip[wave][t][4] = r4; strip[wave][t][5] = r5; strip[wave][t][6] = r6;
    }
  }
  __syncthreads();

  if (tid < T) {
    float f0 = 0.f, f1 = 0.f, f2 = 0.f, f3 = 0.f, f4 = 0.f, f5 = 0.f, f6 = 0.f;
#pragma unroll
    for (int w = 0; w < 8; w++) {
      float4 a = *(float4*)&strip[w][tid][0];
      float4 bq = *(float4*)&strip[w][tid][4];
      f0 += a.x; f1 += a.y; f2 += a.z; f3 += a.w;
      f4 += bq.x; f5 += bq.y; f6 += bq.z;
    }
    float inv = 1.0f / (f5 + f6);
    float* o8 = &att[(size_t)b * (T * 8) + (size_t)tid * 8];
    o8[0] = f0 * inv; o8[1] = f1 * inv; o8[2] = f2 * inv;
    o8[3] = f3 * inv; o8[4] = f4 * inv;
    o8[5] = 0.f; o8[6] = f5 * inv; o8[7] = f6 * inv;
  }
}

// ---------------- Phase B: LSTM -- pk-FMA, dense cell phase, temb table ----------------
// ROUND-13 (from round-12's VALUBusy=85% profile): (1) v2f pk_fma halves main
// FMA issue 320->160; (2) CELL moved from exec-masked s==0 (16 waves x ~300
// insts at 1/8 lanes) to a dense phase on threads 0-511 via a gates-in-LDS
// exchange; (3) all per-t TEMB (f64 mul + sincos) replaced by a 101-entry LDS
// table (args are always k*0.1); (4) weight pointer blurred as SGPR ("+s") so
// loads are saddr-form. Streaming floor: 327 KB/CU/t from L2 ~= 2.4 us/t.
#define XE(tb, b, e) (((tb) * 4 + (b)) * 160 + (e))

__global__ __attribute__((amdgpu_flat_work_group_size(1024, 1024)))
void lstm_k(const float* __restrict__ att,
            const float* __restrict__ u,
            const float4* __restrict__ wT,
            const float* __restrict__ bih,
            const float* __restrict__ bhh,
            const float* __restrict__ w1g,
            const float* __restrict__ b1g,
            const float* __restrict__ w2g,
            const float* __restrict__ b2g,
            float* __restrict__ out) {
  const int tid = threadIdx.x;
  const int bg = blockIdx.x * 4;
  const int s = tid & 7;                     // column-segment of this thread
  const int q = tid >> 3;                    // channel (P1 role)
  const int lane = tid & 63;
  const int s5 = s * 5;

  __shared__ float4 xls4[2][4][40];          // dbuf [x(21)|pad|hx(128)|pad] per batch
  __shared__ float4 glds[4][128];            // gate exchange: (batch, channel) -> {i,f,g,o}
  __shared__ float red2[4][2];               // head partials: 2 waves per batch
  __shared__ float tembT[101][5];            // temb(k*0.1) table
  __shared__ float uT[4][100];               // staged uniforms
  __shared__ int stL[2][4], stD[2][4], stH[2][4];
  float* xf = (float*)xls4;

  // cell-role constants (ch = tid&127; used only by tid<512 but computed by all)
  const int chI = tid & 127;
  float bbc0 = bih[chI] + bhh[chI];
  float bbc1 = bih[chI + 128] + bhh[chI + 128];
  float bbc2 = bih[chI + 256] + bhh[chI + 256];
  float bbc3 = bih[chI + 384] + bhh[chI + 384];
  float wvc = 0.f;
#pragma unroll
  for (int j = 0; j < 5; j++) wvc = fmaf(w2g[j], w1g[j * HID + chI], wvc);
  float hconst = b2g[0];
#pragma unroll
  for (int j = 0; j < 5; j++) hconst = fmaf(w2g[j], b1g[j], hconst);
  asm volatile("" : "+v"(bbc0), "+v"(bbc1), "+v"(bbc2), "+v"(bbc3),
                    "+v"(wvc), "+v"(hconst));
  float cx = 0.f;

  // init: zero x buffers, build temb table, stage u, init event state
  for (int i = tid; i < 2 * 4 * 160; i += 1024) xf[i] = 0.f;
  if (tid < 101) {
    double td = (double)tid * 0.1;
    TEMB(td);
    tembT[tid][0] = d0; tembT[tid][1] = d1; tembT[tid][2] = d2;
    tembT[tid][3] = d3; tembT[tid][4] = d4;
  }
  for (int i = tid; i < 400; i += 1024) {
    int b = i / 100, tt = i - b * 100;
    uT[b][tt] = u[(size_t)(bg + b) * T + tt];
  }
  if (tid < 4) { stL[0][tid] = 0; stD[0][tid] = 0; stH[0][tid] = 0; }
  __syncthreads();

  // x(t=0): att + ct_emb(0.1)=tembT[1]; m_emb stays 0 (no event yet)
  if (tid < 32) {
    int b = tid >> 3, j = tid & 7;
    xf[XE(0, b, j)] = att[(size_t)(bg + b) * (T * 8) + j];
  } else if (tid >= 64 && tid < 84) {
    int s2 = tid - 64, b = s2 / 5, j = s2 % 5;
    xf[XE(0, b, 16 + j)] = tembT[1][j];
  }
  __syncthreads();

  const float4* wTp = wT;   // SGPR-blurred per t: saddr loads, no LICM re-hoist

#define FM1(g, b) \
  a##g##b = __builtin_elementwise_fma(mkv2(w##g.x, w##g.y), xlo, a##g##b); \
  a##g##b = __builtin_elementwise_fma(mkv2(w##g.z, w##g.w), xhi, a##g##b);

#define CHB(b, c) { \
    float4 xb = xls4[tb][b][s5 + (c)]; \
    v2f xlo = mkv2(xb.x, xb.y), xhi = mkv2(xb.z, xb.w); \
    FM1(0, b) FM1(1, b) FM1(2, b) FM1(3, b) }

#define CH(c) { \
    float4 w0 = wTp[(0 * 5 + (c)) * 1024 + tid]; \
    float4 w1 = wTp[(1 * 5 + (c)) * 1024 + tid]; \
    float4 w2 = wTp[(2 * 5 + (c)) * 1024 + tid]; \
    float4 w3 = wTp[(3 * 5 + (c)) * 1024 + tid]; \
    CHB(0, c) CHB(1, c) CHB(2, c) CHB(3, c) }

#define CALCEV(bb) \
    float z_ = hconst + red2[bb][0] + red2[bb][1]; \
    float hz_ = 1.f / (1.f + expf(-z_)); \
    int ev_ = (uT[bb][t] < hz_) ? 1 : 0; \
    int lastp_ = ev_ ? (t + 1) : stL[tb][bb]; \
    int hasp_ = stH[tb][bb] | ev_; \
    int dynp_ = ev_ ? 0 : (stD[tb][bb] + 1);

  for (int t = 0; t < T; t++) {
    const int tb = t & 1, tb1 = tb ^ 1;
    asm volatile("" : "+s"(wTp));

    // ---- P1: pk-FMA partials over this thread's 20-col segment ----
    v2f z2 = mkv2(0.f, 0.f);
    v2f a00 = z2, a01 = z2, a02 = z2, a03 = z2,
        a10 = z2, a11 = z2, a12 = z2, a13 = z2,
        a20 = z2, a21 = z2, a22 = z2, a23 = z2,
        a30 = z2, a31 = z2, a32 = z2, a33 = z2;
    CH(0) CH(1) CH(2) CH(3) CH(4)

    float h00 = a00.x + a00.y, h01 = a01.x + a01.y, h02 = a02.x + a02.y, h03 = a03.x + a03.y;
    float h10 = a10.x + a10.y, h11 = a11.x + a11.y, h12 = a12.x + a12.y, h13 = a13.x + a13.y;
    float h20 = a20.x + a20.y, h21 = a21.x + a21.y, h22 = a22.x + a22.y, h23 = a23.x + a23.y;
    float h30 = a30.x + a30.y, h31 = a31.x + a31.y, h32 = a32.x + a32.y, h33 = a33.x + a33.y;
    RED8(h00) RED8(h01) RED8(h02) RED8(h03)
    RED8(h10) RED8(h11) RED8(h12) RED8(h13)
    RED8(h20) RED8(h21) RED8(h22) RED8(h23)
    RED8(h30) RED8(h31) RED8(h32) RED8(h33)
    if (s == 0) {
      glds[0][q] = make_float4(h00, h10, h20, h30);
      glds[1][q] = make_float4(h01, h11, h21, h31);
      glds[2][q] = make_float4(h02, h12, h22, h32);
      glds[3][q] = make_float4(h03, h13, h23, h33);
    }
    __syncthreads();

    // ---- P2: dense cell update (threads 0-511, full lanes) ----
    if (tid < 512) {
      int b = tid >> 7;
      float4 g4 = glds[b][chI];
      float gi = g4.x + bbc0, gf = g4.y + bbc1, gG = g4.z + bbc2, go = g4.w + bbc3;
      cx = sig(gf) * cx + sig(gi) * tanhf(gG);
      float hn = sig(go) * tanhf(cx);
      xf[XE(tb1, b, 24 + chI)] = hn;
      float pb = wred(wvc * hn);
      if (lane == 0) red2[b][(tid >> 6) & 1] = pb;
    }
    __syncthreads();

    // ---- P3: hazard/event finalize + build x(t+1) via temb table ----
    if (tid < 4) {
      int b = tid;
      CALCEV(b);
      out[(size_t)t * BTOT + bg + b] = hz_;
      out[(size_t)T * BTOT + (size_t)t * BTOT + bg + b] = ev_ ? 1.f : 0.f;
      stL[tb1][b] = lastp_; stH[tb1][b] = hasp_; stD[tb1][b] = dynp_;
    }
    if (t < T - 1) {
      if (tid < 32) {
        int b = tid >> 3, j = tid & 7;
        xf[XE(tb1, b, j)] = att[(size_t)(bg + b) * (T * 8) + (size_t)(t + 1) * 8 + j];
      } else if (tid < 52) {
        int s2 = tid - 32, b = s2 / 5, j = s2 % 5;
        CALCEV(b);
        xf[XE(tb1, b, 8 + j)] = hasp_ ? tembT[lastp_][j] : 0.f;
      } else if (tid < 64) {
        int s2 = tid - 52, b = s2 / 3, j = s2 % 3;
        CALCEV(b);
        xf[XE(tb1, b, 13 + j)] = (j == 0 && hasp_) ? 1.f : 0.f;
      } else if (tid < 84) {
        int s2 = tid - 64, b = s2 / 5, j = s2 % 5;
        CALCEV(b);
        xf[XE(tb1, b, 16 + j)] = tembT[dynp_ + 1][j];
      }
    }
    __syncthreads();
  }
#undef CALCEV
#undef CH
#undef CHB
#undef FM1
}

extern "C" void kernel_launch(void* const* d_in, const int* in_sizes, int n_in,
                              void* d_out, int out_size, void* d_ws, size_t ws_size,
                              hipStream_t stream) {
  const float* ta1 = (const float*)d_in[0];
  const float* ta2 = (const float*)d_in[1];
  const float* u   = (const float*)d_in[2];
  const float* Wih = (const float*)d_in[3];
  const float* Whh = (const float*)d_in[4];
  const float* bih = (const float*)d_in[5];
  const float* bhh = (const float*)d_in[6];
  const float* w1  = (const float*)d_in[7];
  const float* b1  = (const float*)d_in[8];
  const float* w2  = (const float*)d_in[9];
  const float* b2  = (const float*)d_in[10];
  float* out = (float*)d_out;
  float4* wsT = (float4*)d_ws;                           // 327,680 B
  float* att = (float*)d_ws + ATT_OFF_FLOATS;            // 3.28 MB

  wprep_k<<<dim3(20), dim3(1024), 0, stream>>>(Wih, Whh, wsT);
  attn_k<<<dim3(BTOT), dim3(512), 0, stream>>>(ta1, ta2, att);
  lstm_k<<<dim3(BTOT / 4), dim3(1024), 0, stream>>>(att, u, wsT, bih, bhh,
                                                    w1, b1, w2, b2, out);
}

// Round 14
// 729.087 us; speedup vs baseline: 8.0362x; 1.1455x over previous
//
#include <hip/hip_runtime.h>
#include <math.h>

#define BTOT 1024
#define LEN  2048
#define T    100
#define HID  128

// time-embedding dim constants (f64 argument scaling, f32 sincos)
#define C1 0.025118864315095794
#define C2 6.309573444801933e-04
#define C3 1.5848931924611134e-05
#define C4 3.9810717055349735e-07

#define TEMB(td) \
  float d0 = sinf((float)(td)); \
  float d1 = cosf((float)((td) * C1)); \
  float d2 = sinf((float)((td) * C2)); \
  float d3 = cosf((float)((td) * C3)); \
  float d4 = sinf((float)((td) * C4));

__device__ __forceinline__ float sig(float x) { return 1.0f / (1.0f + expf(-x)); }

using v2f = __attribute__((ext_vector_type(2))) float;
__device__ __forceinline__ v2f mkv2(float a, float b) { v2f r; r.x = a; r.y = b; return r; }

// DPP-based add: x + x_from_permuted_lane (VALU pipe).
template <int CTRL>
__device__ __forceinline__ float dppadd(float x) {
  int r = __builtin_amdgcn_update_dpp(0, __float_as_int(x), CTRL, 0xF, 0xF, false);
  return x + __int_as_float(r);
}
// full 64-lane sum; result valid in lane 0.
__device__ __forceinline__ float wred(float x) {
  x = dppadd<0xB1>(x);    // quad_perm xor1
  x = dppadd<0x4E>(x);    // quad_perm xor2
  x = dppadd<0x124>(x);   // row_ror:4
  x = dppadd<0x128>(x);   // row_ror:8
  x += __shfl_xor(x, 16);
  x += __shfl_xor(x, 32);
  return x;
}
// 4-lane quad sum (quad_perm only -- direction-unambiguous XOR semantics).
#define RED4(x) { x = dppadd<0xB1>(x); x = dppadd<0x4E>(x); }

// AGPR stash/read: the "a" constraint allocates in the ACCUMULATOR half of
// the unified file, OUTSIDE the 64-arch-VGPR budget the allocator has been
// hard-locked to for 8 rounds. Weights live here across all 100 iterations.
#define AGSTASH(a_, v_) asm volatile("v_accvgpr_write_b32 %0, %1" : "=a"(a_) : "v"(v_))
#define AGREAD(v_, a_)  asm volatile("v_accvgpr_read_b32 %0, %1" : "=v"(v_) : "a"(a_))

// ---------------- Phase A: attention (unchanged from rounds 12-13, passed) ----------------
__global__ __attribute__((amdgpu_flat_work_group_size(512, 512)))
void attn_k(const float* __restrict__ ta1,
            const float* __restrict__ ta2,
            float* __restrict__ att) {
  const int b = blockIdx.x, tid = threadIdx.x;
  const int wave = tid >> 6, lane = tid & 63;

  __shared__ float qlds[T][8];
  __shared__ float strip[8][T][8];

  if (tid < T) {
    double ct = (double)(tid + 1) * 0.1;
    TEMB(ct);
    qlds[tid][0] = d0 * 0.35355339059327373f;  // fold 1/sqrt(8)
    qlds[tid][1] = d1 * 0.35355339059327373f;
    qlds[tid][2] = d2 * 0.35355339059327373f;
    qlds[tid][3] = d3 * 0.35355339059327373f;
    qlds[tid][4] = d4 * 0.35355339059327373f;
  }

#define E5(i) float e##i##_0, e##i##_1, e##i##_2, e##i##_3, e##i##_4;
  E5(0) E5(1) E5(2) E5(3) E5(4) E5(5) E5(6) E5(7)
#undef E5
#define STAGE(i, expr) { double td_ = (double)(expr); \
    e##i##_0 = sinf((float)td_); \
    e##i##_1 = cosf((float)(td_ * C1)); \
    e##i##_2 = sinf((float)(td_ * C2)); \
    e##i##_3 = cosf((float)(td_ * C3)); \
    e##i##_4 = sinf((float)(td_ * C4)); }
  STAGE(0, ta1[b * LEN + tid +    0])
  STAGE(1, ta1[b * LEN + tid +  512])
  STAGE(2, ta1[b * LEN + tid + 1024])
  STAGE(3, ta1[b * LEN + tid + 1536])
  STAGE(4, ta2[b * LEN + tid +    0])
  STAGE(5, ta2[b * LEN + tid +  512])
  STAGE(6, ta2[b * LEN + tid + 1024])
  STAGE(7, ta2[b * LEN + tid + 1536])
#undef STAGE
#define PIN5(i) asm volatile("" : "+v"(e##i##_0), "+v"(e##i##_1), \
    "+v"(e##i##_2), "+v"(e##i##_3), "+v"(e##i##_4));
  PIN5(0) PIN5(1) PIN5(2) PIN5(3) PIN5(4) PIN5(5) PIN5(6) PIN5(7)
#undef PIN5

  __syncthreads();

  for (int t = 0; t < T; t++) {
    const float4 qv = *(const float4*)&qlds[t][0];
    const float q4 = qlds[t][4];
    float Wx = 0.f, Wy = 0.f, Wz = 0.f, Ww = 0.f, W4 = 0.f, sA = 0.f, sB = 0.f;
#define EV(i, S) { \
    float s = fmaf(qv.x, e##i##_0, fmaf(qv.y, e##i##_1, \
              fmaf(qv.z, e##i##_2, fmaf(qv.w, e##i##_3, q4 * e##i##_4)))); \
    float e = __expf(s); S += e; \
    Wx = fmaf(e, e##i##_0, Wx); Wy = fmaf(e, e##i##_1, Wy); \
    Wz = fmaf(e, e##i##_2, Wz); Ww = fmaf(e, e##i##_3, Ww); \
    W4 = fmaf(e, e##i##_4, W4); }
    EV(0, sA) EV(1, sA) EV(2, sA) EV(3, sA)
    EV(4, sB) EV(5, sB) EV(6, sB) EV(7, sB)
#undef EV

    float r0 = wred(Wx), r1 = wred(Wy), r2 = wred(Wz), r3 = wred(Ww);
    float r4 = wred(W4), r5 = wred(sA), r6 = wred(sB);
    if (lane == 0) {
      *(float4*)&strip[wave][t][0] = make_float4(r0, r1, r2, r3);
      strip[wave][t][4] = r4; strip[wave][t][5] = r5; strip[wave][t][6] = r6;
    }
  }
  __syncthreads();

  if (tid < T) {
    float f0 = 0.f, f1 = 0.f, f2 = 0.f, f3 = 0.f, f4 = 0.f, f5 = 0.f, f6 = 0.f;
#pragma unroll
    for (int w = 0; w < 8; w++) {
      float4 a = *(float4*)&strip[w][tid][0];
      float4 bq = *(float4*)&strip[w][tid][4];
      f0 += a.x; f1 += a.y; f2 += a.z; f3 += a.w;
      f4 += bq.x; f5 += bq.y; f6 += bq.z;
    }
    float inv = 1.0f / (f5 + f6);
    float* o8 = &att[(size_t)b * (T * 8) + (size_t)tid * 8];
    o8[0] = f0 * inv; o8[1] = f1 * inv; o8[2] = f2 * inv;
    o8[3] = f3 * inv; o8[4] = f4 * inv;
    o8[5] = 0.f; o8[6] = f5 * inv; o8[7] = f6 * inv;
  }
}

// ---------------- Phase B: LSTM -- AGPR-resident weights, 512 threads ----------------
// ROUND-14 (from r13's profile: VALUBusy 54%, the rest = per-t 320 KB weight
// restream through a 32 KB L1 + L2 latency at 4 waves/SIMD): weights are
// loop-INVARIANT, so park them in AGPRs. 512-thread block = 8 waves = 2/SIMD
// -> 256 regs/thread of unified file available: 160 AGPR weights + ~60 arch.
// Thread (q, s in [0,4)): channel q's 4 gate rows x 40-col segment.
// Per t: zero VMEM; 40 ds_read_b128 x-broadcasts/thread (320 wave-insts/CU
// ~= 3.8K cyc -> new floor ~1.6 us/t). RED4 quad reduce; dense cell on all
// 512 threads (4 batches x 128 channels exactly).
#define XE(tb, b, e) (((tb) * 4 + (b)) * 160 + (e))

__global__ __attribute__((amdgpu_flat_work_group_size(512, 512), amdgpu_waves_per_eu(2, 4)))
void lstm_k(const float* __restrict__ att,
            const float* __restrict__ u,
            const float* __restrict__ Wih,
            const float* __restrict__ Whh,
            const float* __restrict__ bih,
            const float* __restrict__ bhh,
            const float* __restrict__ w1g,
            const float* __restrict__ b1g,
            const float* __restrict__ w2g,
            const float* __restrict__ b2g,
            float* __restrict__ out) {
  const int tid = threadIdx.x;
  const int bg = blockIdx.x * 4;
  const int q = tid >> 2, s = tid & 3;       // channel, 40-col segment
  const int lane = tid & 63;
  const int s10 = s * 10;

  __shared__ float4 xls4[2][4][40];          // dbuf [x(21)|pad|hx(128)|pad(8)] per batch
  __shared__ float4 glds[4][128];            // gate exchange: (batch, channel) -> {i,f,g,o}
  __shared__ float red2[4][2];               // head partials: 2 waves per batch
  __shared__ float tembT[101][5];            // temb(k*0.1) table
  __shared__ float uT[4][100];               // staged uniforms
  __shared__ int stL[2][4], stD[2][4], stH[2][4];
  float* xf = (float*)xls4;

  // ---- one-time: weights into AGPRs (gathered loads, amortized) ----
#define DECL4(g, c) float agw##g##_##c##_0, agw##g##_##c##_1, agw##g##_##c##_2, agw##g##_##c##_3;
  DECL4(0,0) DECL4(0,1) DECL4(0,2) DECL4(0,3) DECL4(0,4) DECL4(0,5) DECL4(0,6) DECL4(0,7) DECL4(0,8) DECL4(0,9)
  DECL4(1,0) DECL4(1,1) DECL4(1,2) DECL4(1,3) DECL4(1,4) DECL4(1,5) DECL4(1,6) DECL4(1,7) DECL4(1,8) DECL4(1,9)
  DECL4(2,0) DECL4(2,1) DECL4(2,2) DECL4(2,3) DECL4(2,4) DECL4(2,5) DECL4(2,6) DECL4(2,7) DECL4(2,8) DECL4(2,9)
  DECL4(3,0) DECL4(3,1) DECL4(3,2) DECL4(3,3) DECL4(3,4) DECL4(3,5) DECL4(3,6) DECL4(3,7) DECL4(3,8) DECL4(3,9)
#undef DECL4
#define LD4(g, c) { \
    int E_ = 40 * s + 4 * (c); \
    float4 wv4_; \
    if (E_ >= 24 && E_ < 152) { \
      wv4_ = *(const float4*)(Whh + (size_t)(q + 128 * (g)) * HID + (E_ - 24)); \
    } else if (E_ < 24) { \
      wv4_.x = (E_ + 0 < 21) ? Wih[(q + 128 * (g)) * 21 + E_ + 0] : 0.f; \
      wv4_.y = (E_ + 1 < 21) ? Wih[(q + 128 * (g)) * 21 + E_ + 1] : 0.f; \
      wv4_.z = (E_ + 2 < 21) ? Wih[(q + 128 * (g)) * 21 + E_ + 2] : 0.f; \
      wv4_.w = (E_ + 3 < 21) ? Wih[(q + 128 * (g)) * 21 + E_ + 3] : 0.f; \
    } else { wv4_ = make_float4(0.f, 0.f, 0.f, 0.f); } \
    AGSTASH(agw##g##_##c##_0, wv4_.x); AGSTASH(agw##g##_##c##_1, wv4_.y); \
    AGSTASH(agw##g##_##c##_2, wv4_.z); AGSTASH(agw##g##_##c##_3, wv4_.w); }
  LD4(0,0) LD4(0,1) LD4(0,2) LD4(0,3) LD4(0,4) LD4(0,5) LD4(0,6) LD4(0,7) LD4(0,8) LD4(0,9)
  LD4(1,0) LD4(1,1) LD4(1,2) LD4(1,3) LD4(1,4) LD4(1,5) LD4(1,6) LD4(1,7) LD4(1,8) LD4(1,9)
  LD4(2,0) LD4(2,1) LD4(2,2) LD4(2,3) LD4(2,4) LD4(2,5) LD4(2,6) LD4(2,7) LD4(2,8) LD4(2,9)
  LD4(3,0) LD4(3,1) LD4(3,2) LD4(3,3) LD4(3,4) LD4(3,5) LD4(3,6) LD4(3,7) LD4(3,8) LD4(3,9)
#undef LD4

  // cell-role constants (ch = tid&127, batch = tid>>7; all 512 threads)
  const int chI = tid & 127;
  float bbc0 = bih[chI] + bhh[chI];
  float bbc1 = bih[chI + 128] + bhh[chI + 128];
  float bbc2 = bih[chI + 256] + bhh[chI + 256];
  float bbc3 = bih[chI + 384] + bhh[chI + 384];
  float wvc = 0.f;
#pragma unroll
  for (int j = 0; j < 5; j++) wvc = fmaf(w2g[j], w1g[j * HID + chI], wvc);
  float hconst = b2g[0];
#pragma unroll
  for (int j = 0; j < 5; j++) hconst = fmaf(w2g[j], b1g[j], hconst);
  asm volatile("" : "+v"(bbc0), "+v"(bbc1), "+v"(bbc2), "+v"(bbc3),
                    "+v"(wvc), "+v"(hconst));
  float cx = 0.f;

  // init: zero x buffers, temb table, stage u, event state
  for (int i = tid; i < 2 * 4 * 160; i += 512) xf[i] = 0.f;
  if (tid < 101) {
    double td = (double)tid * 0.1;
    TEMB(td);
    tembT[tid][0] = d0; tembT[tid][1] = d1; tembT[tid][2] = d2;
    tembT[tid][3] = d3; tembT[tid][4] = d4;
  }
  for (int i = tid; i < 400; i += 512) {
    int b = i / 100, tt = i - b * 100;
    uT[b][tt] = u[(size_t)(bg + b) * T + tt];
  }
  if (tid < 4) { stL[0][tid] = 0; stD[0][tid] = 0; stH[0][tid] = 0; }
  __syncthreads();

  // x(t=0): att + ct_emb(0.1)=tembT[1]; m_emb stays 0 (no event yet)
  if (tid < 32) {
    int b = tid >> 3, j = tid & 7;
    xf[XE(0, b, j)] = att[(size_t)(bg + b) * (T * 8) + j];
  } else if (tid >= 64 && tid < 84) {
    int s2 = tid - 64, b = s2 / 5, j = s2 % 5;
    xf[XE(0, b, 16 + j)] = tembT[1][j];
  }
  __syncthreads();

#define GFMA(g, c) { \
    float t0_, t1_, t2_, t3_; \
    AGREAD(t0_, agw##g##_##c##_0); AGREAD(t1_, agw##g##_##c##_1); \
    AGREAD(t2_, agw##g##_##c##_2); AGREAD(t3_, agw##g##_##c##_3); \
    v2f wlo_ = mkv2(t0_, t1_), whi_ = mkv2(t2_, t3_); \
    a##g##0 = __builtin_elementwise_fma(wlo_, x0lo, a##g##0); \
    a##g##0 = __builtin_elementwise_fma(whi_, x0hi, a##g##0); \
    a##g##1 = __builtin_elementwise_fma(wlo_, x1lo, a##g##1); \
    a##g##1 = __builtin_elementwise_fma(whi_, x1hi, a##g##1); \
    a##g##2 = __builtin_elementwise_fma(wlo_, x2lo, a##g##2); \
    a##g##2 = __builtin_elementwise_fma(whi_, x2hi, a##g##2); \
    a##g##3 = __builtin_elementwise_fma(wlo_, x3lo, a##g##3); \
    a##g##3 = __builtin_elementwise_fma(whi_, x3hi, a##g##3); }

#define CH(c) { \
    float4 xb0_ = xls4[tb][0][s10 + (c)], xb1_ = xls4[tb][1][s10 + (c)], \
           xb2_ = xls4[tb][2][s10 + (c)], xb3_ = xls4[tb][3][s10 + (c)]; \
    v2f x0lo = mkv2(xb0_.x, xb0_.y), x0hi = mkv2(xb0_.z, xb0_.w); \
    v2f x1lo = mkv2(xb1_.x, xb1_.y), x1hi = mkv2(xb1_.z, xb1_.w); \
    v2f x2lo = mkv2(xb2_.x, xb2_.y), x2hi = mkv2(xb2_.z, xb2_.w); \
    v2f x3lo = mkv2(xb3_.x, xb3_.y), x3hi = mkv2(xb3_.z, xb3_.w); \
    GFMA(0, c) GFMA(1, c) GFMA(2, c) GFMA(3, c) }

#define CALCEV(bb) \
    float z_ = hconst + red2[bb][0] + red2[bb][1]; \
    float hz_ = 1.f / (1.f + expf(-z_)); \
    int ev_ = (uT[bb][t] < hz_) ? 1 : 0; \
    int lastp_ = ev_ ? (t + 1) : stL[tb][bb]; \
    int hasp_ = stH[tb][bb] | ev_; \
    int dynp_ = ev_ ? 0 : (stD[tb][bb] + 1);

  for (int t = 0; t < T; t++) {
    const int tb = t & 1, tb1 = tb ^ 1;

    // ---- P1: pk-FMA over this thread's 40-col segment (weights from AGPR) ----
    v2f z2 = mkv2(0.f, 0.f);
    v2f a00 = z2, a01 = z2, a02 = z2, a03 = z2,
        a10 = z2, a11 = z2, a12 = z2, a13 = z2,
        a20 = z2, a21 = z2, a22 = z2, a23 = z2,
        a30 = z2, a31 = z2, a32 = z2, a33 = z2;
    CH(0) CH(1) CH(2) CH(3) CH(4) CH(5) CH(6) CH(7) CH(8) CH(9)

    float h00 = a00.x + a00.y, h01 = a01.x + a01.y, h02 = a02.x + a02.y, h03 = a03.x + a03.y;
    float h10 = a10.x + a10.y, h11 = a11.x + a11.y, h12 = a12.x + a12.y, h13 = a13.x + a13.y;
    float h20 = a20.x + a20.y, h21 = a21.x + a21.y, h22 = a22.x + a22.y, h23 = a23.x + a23.y;
    float h30 = a30.x + a30.y, h31 = a31.x + a31.y, h32 = a32.x + a32.y, h33 = a33.x + a33.y;
    RED4(h00) RED4(h01) RED4(h02) RED4(h03)
    RED4(h10) RED4(h11) RED4(h12) RED4(h13)
    RED4(h20) RED4(h21) RED4(h22) RED4(h23)
    RED4(h30) RED4(h31) RED4(h32) RED4(h33)
    if (s == 0) {   // quad lane 0 holds all 4 gates x 4 batches for channel q
      glds[0][q] = make_float4(h00, h10, h20, h30);
      glds[1][q] = make_float4(h01, h11, h21, h31);
      glds[2][q] = make_float4(h02, h12, h22, h32);
      glds[3][q] = make_float4(h03, h13, h23, h33);
    }
    __syncthreads();

    // ---- P2: dense cell update (all 512 threads = 4 batches x 128 channels) ----
    {
      int b = tid >> 7;
      float4 g4 = glds[b][chI];
      float gi = g4.x + bbc0, gf = g4.y + bbc1, gG = g4.z + bbc2, go = g4.w + bbc3;
      cx = sig(gf) * cx + sig(gi) * tanhf(gG);
      float hn = sig(go) * tanhf(cx);
      xf[XE(tb1, b, 24 + chI)] = hn;
      float pb = wred(wvc * hn);
      if (lane == 0) red2[b][(tid >> 6) & 1] = pb;
    }
    __syncthreads();

    // ---- P3: hazard/event finalize + build x(t+1) via temb table ----
    if (tid < 4) {
      int b = tid;
      CALCEV(b);
      out[(size_t)t * BTOT + bg + b] = hz_;
      out[(size_t)T * BTOT + (size_t)t * BTOT + bg + b] = ev_ ? 1.f : 0.f;
      stL[tb1][b] = lastp_; stH[tb1][b] = hasp_; stD[tb1][b] = dynp_;
    }
    if (t < T - 1) {
      if (tid < 32) {
        int b = tid >> 3, j = tid & 7;
        xf[XE(tb1, b, j)] = att[(size_t)(bg + b) * (T * 8) + (size_t)(t + 1) * 8 + j];
      } else if (tid < 52) {
        int s2 = tid - 32, b = s2 / 5, j = s2 % 5;
        CALCEV(b);
        xf[XE(tb1, b, 8 + j)] = hasp_ ? tembT[lastp_][j] : 0.f;
      } else if (tid < 64) {
        int s2 = tid - 52, b = s2 / 3, j = s2 % 3;
        CALCEV(b);
        xf[XE(tb1, b, 13 + j)] = (j == 0 && hasp_) ? 1.f : 0.f;
      } else if (tid < 84) {
        int s2 = tid - 64, b = s2 / 5, j = s2 % 5;
        CALCEV(b);
        xf[XE(tb1, b, 16 + j)] = tembT[dynp_ + 1][j];
      }
    }
    __syncthreads();
  }
#undef CALCEV
#undef CH
#undef GFMA
}

extern "C" void kernel_launch(void* const* d_in, const int* in_sizes, int n_in,
                              void* d_out, int out_size, void* d_ws, size_t ws_size,
                              hipStream_t stream) {
  const float* ta1 = (const float*)d_in[0];
  const float* ta2 = (const float*)d_in[1];
  const float* u   = (const float*)d_in[2];
  const float* Wih = (const float*)d_in[3];
  const float* Whh = (const float*)d_in[4];
  const float* bih = (const float*)d_in[5];
  const float* bhh = (const float*)d_in[6];
  const float* w1  = (const float*)d_in[7];
  const float* b1  = (const float*)d_in[8];
  const float* w2  = (const float*)d_in[9];
  const float* b2  = (const float*)d_in[10];
  float* out = (float*)d_out;
  float* att = (float*)d_ws;   // 1024*100*8 floats = 3.28 MB scratch

  attn_k<<<dim3(BTOT), dim3(512), 0, stream>>>(ta1, ta2, att);
  lstm_k<<<dim3(BTOT / 4), dim3(512), 0, stream>>>(att, u, Wih, Whh, bih, bhh,
                                                   w1, b1, w2, b2, out);
}